// Round 11
// baseline (624.608 us; speedup 1.0000x reference)
//
#include <hip/hip_runtime.h>
#include <hip/hip_bf16.h>

// ---------------------------------------------------------------------------
// 2-layer GCN. MFMA bf16 GEMM (W hi+lo split, f32 input fused for layer 1),
// bf16 messages, bucket-built CSC with packed uint edges, XCD-sliced agg.
//   dinv = rsqrt(deg+1);  y' = bf16( (x @ (Whi+Wlo)) * dinv[row] )
//   agg[d] = y'[d] + sum y'[src];  h = relu(agg*dinv + b)
// ---------------------------------------------------------------------------

#define DIM 128
#define BSH 9                    // bucket shift: 512 dst/bucket
#define NBKT 196                 // ceil(100000 / 512)

typedef __attribute__((ext_vector_type(8))) short bf16x8;
typedef __attribute__((ext_vector_type(4))) float f32x4;

static __device__ __forceinline__ ushort bfbits(float f) {
    __hip_bfloat16 h = __float2bfloat16(f);
    return *(ushort*)&h;
}

// ---------------- bucket CSC pipeline --------------------------------------

__global__ __launch_bounds__(256) void k_bcount(const int* __restrict__ dst,
                                                int E, int* __restrict__ bcnt) {
    __shared__ int h[NBKT];
    int t = threadIdx.x;
    for (int b = t; b < NBKT; b += 256) h[b] = 0;
    __syncthreads();
    for (int e = blockIdx.x * 256 + t; e < E; e += gridDim.x * 256)
        atomicAdd(&h[dst[e] >> BSH], 1);
    __syncthreads();
    for (int b = t; b < NBKT; b += 256)
        if (h[b]) atomicAdd(&bcnt[b], h[b]);
}

__global__ void k_bscan(const int* __restrict__ bcnt, int* __restrict__ bbase,
                        int* __restrict__ bcur) {
    __shared__ int a[256], c[256];
    int t = threadIdx.x;
    int v = (t < NBKT) ? bcnt[t] : 0;
    a[t] = v;
    __syncthreads();
    int* A = a; int* B = c;
    for (int off = 1; off < 256; off <<= 1) {
        B[t] = A[t] + (t >= off ? A[t - off] : 0);
        __syncthreads();
        int* tmp = A; A = B; B = tmp;
    }
    int incl = A[t];
    if (t < NBKT) { int ex = incl - v; bbase[t] = ex; bcur[t] = ex; }
    if (t == NBKT - 1) bbase[NBKT] = incl;
}

// C: scatter packed edges (dstLocal<<17 | src) into bucket-grouped order.
__global__ __launch_bounds__(256) void k_bscatter(
    const int* __restrict__ src, const int* __restrict__ dst, int E,
    int* __restrict__ bcur, uint* __restrict__ out) {
    __shared__ uint stage[NBKT * 32];
    __shared__ int scnt[NBKT];
    __shared__ int needflush;
    int t = threadIdx.x;
    for (int b = t; b < NBKT; b += 256) scnt[b] = 0;
    if (t == 0) needflush = 0;
    __syncthreads();

    int per = (E + gridDim.x - 1) / gridDim.x;
    int s0 = blockIdx.x * per;
    int s1 = min(E, s0 + per);

    for (int base = s0; base < s1; base += 1024) {
#pragma unroll
        for (int k = 0; k < 4; ++k) {
            int e = base + t + k * 256;
            if (e < s1) {
                int d = dst[e];
                uint pr = ((uint)(d & 511) << 17) | (uint)src[e];
                int b = d >> BSH;
                int slot = atomicAdd(&scnt[b], 1);
                if (slot < 32) {
                    stage[b * 32 + slot] = pr;
                    if (slot == 31) needflush = 1;
                } else {                        // rare overflow: direct path
                    int c = atomicAdd(&bcur[b], 1);
                    out[c] = pr;
                }
            }
        }
        __syncthreads();
        if (needflush) {
            for (int bb = t; bb < NBKT; bb += 256) {
                if (scnt[bb] >= 32) {
                    int cur = atomicAdd(&bcur[bb], 32);
#pragma unroll
                    for (int k = 0; k < 32; ++k) out[cur + k] = stage[bb * 32 + k];
                    scnt[bb] = 0;
                }
            }
            __syncthreads();
            if (t == 0) needflush = 0;
            __syncthreads();
        }
    }
    for (int bb = t; bb < NBKT; bb += 256) {
        int c = scnt[bb]; if (c > 32) c = 32;
        if (c > 0) {
            int cur = atomicAdd(&bcur[bb], c);
            for (int k = 0; k < c; ++k) out[cur + k] = stage[bb * 32 + k];
        }
    }
}

// D: per bucket: local hist + scan -> rowptr/dinv, col scatter in-window.
__global__ __launch_bounds__(256) void k_bcsc(
    const uint* __restrict__ pairs, const int* __restrict__ bbase,
    int* __restrict__ rowptr, float* __restrict__ dinv,
    int* __restrict__ col, int n) {
    __shared__ int lh[512], ls[512];
    int b = blockIdx.x, t = threadIdx.x;
    int p0 = bbase[b], p1 = bbase[b + 1];
    int d0 = b << BSH;

    lh[t] = 0; lh[t + 256] = 0;
    __syncthreads();
    for (int i = p0 + t; i < p1; i += 256)
        atomicAdd(&lh[pairs[i] >> 17], 1);
    __syncthreads();

    int deg0 = lh[t], deg1 = lh[t + 256];
    int* A = lh; int* B = ls;
    for (int off = 1; off < 512; off <<= 1) {
        B[t]       = A[t]       + (t       >= off ? A[t - off]       : 0);
        B[t + 256] = A[t + 256] + (t + 256 >= off ? A[t + 256 - off] : 0);
        __syncthreads();
        int* tmp = A; A = B; B = tmp;
    }
    int ex0 = A[t] - deg0, ex1 = A[t + 256] - deg1;
    __syncthreads();
    B[t] = ex0; B[t + 256] = ex1;                  // cursors

    int nd = d0 + t;
    if (nd < n) { rowptr[nd] = p0 + ex0; dinv[nd] = rsqrtf((float)(deg0 + 1)); }
    nd = d0 + t + 256;
    if (nd < n) { rowptr[nd] = p0 + ex1; dinv[nd] = rsqrtf((float)(deg1 + 1)); }
    if (b == NBKT - 1 && t == 0) rowptr[n] = p1;
    __syncthreads();

    for (int i = p0 + t; i < p1; i += 256) {
        uint pr = pairs[i];
        int slot = p0 + atomicAdd(&B[pr >> 17], 1);
        col[slot] = (int)(pr & 0x1FFFFu);
    }
}

// ---------------- W prep: both layers in one launch ------------------------
__global__ void k_split_w2(const float* __restrict__ W1,
                           const float* __restrict__ W2,
                           ushort* __restrict__ wpk1,
                           ushort* __restrict__ wpk2) {
    int g = blockIdx.x;
    const float* W   = (g < 64) ? W1 : W2;
    ushort* Wpk      = (g < 64) ? wpk1 : wpk2;
    int idx = (g & 63) * 256 + threadIdx.x;     // 0..16383
    int j    = idx & 7;
    int lane = (idx >> 3) & 63;
    int ks   = (idx >> 9) & 3;
    int ct   = idx >> 11;
    int k  = ks * 32 + (lane >> 4) * 8 + j;
    int nn = ct * 16 + (lane & 15);
    float w = W[k * 128 + nn];
    __hip_bfloat16 hi = __float2bfloat16(w);
    float rem = w - __bfloat162float(hi);
    Wpk[idx]         = *(ushort*)&hi;
    Wpk[16384 + idx] = bfbits(rem);
}

// ---------------- MFMA GEMM: y = bf16( (x @ (Whi+Wlo)) * dinv[row] ) -------
template <int INF32>
__global__ __launch_bounds__(256, 2) void k_gemm_mfma(
    const void* __restrict__ xin, const ushort* __restrict__ Wpk,
    const float* __restrict__ dinv, ushort* __restrict__ y,
    int n, int ntiles) {
    __shared__ ushort Wl[32768];
    int t = threadIdx.x;
    {
        const uint4* s4 = (const uint4*)Wpk;
        uint4* d4 = (uint4*)Wl;
#pragma unroll
        for (int i = 0; i < 16; ++i) d4[t + 256 * i] = s4[t + 256 * i];
    }
    __syncthreads();

    const int wave = t >> 6, lane = t & 63;
    const int l15 = lane & 15, lg = lane >> 4;

    for (int tile = blockIdx.x; tile < ntiles; tile += gridDim.x) {
        int row0 = tile * 64 + wave * 16;
        int arow = row0 + l15;
        if (arow >= n) arow = n - 1;

        bf16x8 a[4];
        if (INF32) {
            const float* xp = (const float*)xin + (size_t)arow * 128 + lg * 8;
#pragma unroll
            for (int ks = 0; ks < 4; ++ks) {
                float4 f0 = *(const float4*)(xp + ks * 32);
                float4 f1 = *(const float4*)(xp + ks * 32 + 4);
                bf16x8 av;
                av[0] = (short)bfbits(f0.x); av[1] = (short)bfbits(f0.y);
                av[2] = (short)bfbits(f0.z); av[3] = (short)bfbits(f0.w);
                av[4] = (short)bfbits(f1.x); av[5] = (short)bfbits(f1.y);
                av[6] = (short)bfbits(f1.z); av[7] = (short)bfbits(f1.w);
                a[ks] = av;
            }
        } else {
            const ushort* xp = (const ushort*)xin + (size_t)arow * 128 + lg * 8;
#pragma unroll
            for (int ks = 0; ks < 4; ++ks)
                a[ks] = *(const bf16x8*)(xp + ks * 32);
        }

        f32x4 acc[8];
#pragma unroll
        for (int ct = 0; ct < 8; ++ct) acc[ct] = (f32x4)(0.f);

#pragma unroll
        for (int ks = 0; ks < 4; ++ks) {
#pragma unroll
            for (int ct = 0; ct < 8; ++ct) {
                bf16x8 b = *(const bf16x8*)&Wl[(size_t)((0 * 8 + ct) * 4 + ks) * 512 + lane * 8];
                acc[ct] = __builtin_amdgcn_mfma_f32_16x16x32_bf16(a[ks], b, acc[ct], 0, 0, 0);
            }
#pragma unroll
            for (int ct = 0; ct < 8; ++ct) {
                bf16x8 b = *(const bf16x8*)&Wl[(size_t)((1 * 8 + ct) * 4 + ks) * 512 + lane * 8];
                acc[ct] = __builtin_amdgcn_mfma_f32_16x16x32_bf16(a[ks], b, acc[ct], 0, 0, 0);
            }
        }

#pragma unroll
        for (int r = 0; r < 4; ++r) {
            int row = row0 + lg * 4 + r;
            if (row < n) {
                float dv = dinv[row];
                ushort* yr = y + (size_t)row * 128 + l15;
#pragma unroll
                for (int ct = 0; ct < 8; ++ct)
                    yr[ct * 16] = bfbits(acc[ct][r] * dv);
            }
        }
    }
}

// ---------------- aggregation: XCD-sliced ----------------------------------
// slice = blockIdx & 7 -> lands on XCD (slice) under round-robin dispatch.
// Each XCD gathers only its 16-col sub-array (3.2 MB, fits 4 MB L2).
// Wave = 8 nodes x 8 lanes; lane owns one uint (2 cols) of its node's slice.
template <int MODE>   // 0: bf16 out, 1: f32 out
__global__ __launch_bounds__(256) void k_agg3(
    const ushort* __restrict__ yb, const int* __restrict__ rowptr,
    const int* __restrict__ col, const float* __restrict__ dinv,
    const float* __restrict__ bias, void* __restrict__ outp, int n) {
    int t = threadIdx.x;
    int slice = blockIdx.x & 7;
    int chunk = blockIdx.x >> 3;
    int wave = t >> 6, lane = t & 63;
    int node = chunk * 32 + wave * 8 + (lane >> 3);
    if (node >= n) return;
    int coff = slice * 16 + (lane & 7) * 2;       // column offset (ushort units)

    const ushort* base = yb + coff;
    uint v0 = *(const uint*)(base + (size_t)node * 128);    // self loop
    float ax = __uint_as_float(v0 << 16);
    float ay = __uint_as_float(v0 & 0xffff0000u);

    int lo = rowptr[node], hi = rowptr[node + 1];
    int i = lo;
    for (; i + 4 <= hi; i += 4) {
        int s0 = col[i], s1 = col[i + 1], s2 = col[i + 2], s3 = col[i + 3];
        uint w0 = *(const uint*)(base + (size_t)s0 * 128);
        uint w1 = *(const uint*)(base + (size_t)s1 * 128);
        uint w2 = *(const uint*)(base + (size_t)s2 * 128);
        uint w3 = *(const uint*)(base + (size_t)s3 * 128);
        ax += __uint_as_float(w0 << 16);  ay += __uint_as_float(w0 & 0xffff0000u);
        ax += __uint_as_float(w1 << 16);  ay += __uint_as_float(w1 & 0xffff0000u);
        ax += __uint_as_float(w2 << 16);  ay += __uint_as_float(w2 & 0xffff0000u);
        ax += __uint_as_float(w3 << 16);  ay += __uint_as_float(w3 & 0xffff0000u);
    }
    for (; i < hi; ++i) {
        uint w = *(const uint*)(base + (size_t)col[i] * 128);
        ax += __uint_as_float(w << 16);
        ay += __uint_as_float(w & 0xffff0000u);
    }

    float dv = dinv[node];
    float2 b = ((const float2*)bias)[coff >> 1];
    float ox = fmaxf(ax * dv + b.x, 0.f);
    float oy = fmaxf(ay * dv + b.y, 0.f);

    if (MODE == 0) {
        uint o = ((uint)bfbits(oy) << 16) | (uint)bfbits(ox);
        ((uint*)outp)[(size_t)node * 64 + (coff >> 1)] = o;
    } else {
        ((float2*)outp)[(size_t)node * 64 + (coff >> 1)] = make_float2(ox, oy);
    }
}

// ---------------------------------------------------------------------------

extern "C" void kernel_launch(void* const* d_in, const int* in_sizes, int n_in,
                              void* d_out, int out_size, void* d_ws, size_t ws_size,
                              hipStream_t stream) {
    const float* x  = (const float*)d_in[0];
    const float* W1 = (const float*)d_in[1];
    const float* b1 = (const float*)d_in[2];
    const float* W2 = (const float*)d_in[3];
    const float* b2 = (const float*)d_in[4];
    const int*   ei = (const int*)d_in[5];

    const int n = in_sizes[0] / DIM;     // 100000
    const int E = in_sizes[5] / 2;       // 1600000
    const int* src = ei;
    const int* dst = ei + E;
    float* out = (float*)d_out;

    // workspace carve-up
    char* w = (char*)d_ws;
    ushort* y     = (ushort*)w;  w += (size_t)n * DIM * sizeof(ushort);   // 25.6 MB
    ushort* h     = (ushort*)w;  w += (size_t)n * DIM * sizeof(ushort);   // 25.6 MB
    uint*   bpair = (uint*)w;    w += (size_t)E * sizeof(uint);           // 6.4 MB
    ushort* wpk1  = (ushort*)w;  w += 32768 * sizeof(ushort);
    ushort* wpk2  = (ushort*)w;  w += 32768 * sizeof(ushort);
    float*  dinv  = (float*)w;   w += (size_t)n * sizeof(float);
    int*    rowptr= (int*)w;     w += (size_t)(n + 4) * sizeof(int);
    int*    col   = (int*)w;     w += (size_t)E * sizeof(int);            // 6.4 MB
    int*    bcnt  = (int*)w;     w += NBKT * sizeof(int);
    int*    bbase = (int*)w;     w += (NBKT + 4) * sizeof(int);
    int*    bcur  = (int*)w;     w += NBKT * sizeof(int);

    const int nbAgg  = 8 * ((n + 31) / 32);   // slice-major grid (25000)
    const int ntiles = (n + 63) / 64;
    const int nbGemm = 512;

    // ---- CSC + dinv (bucket pipeline, packed uint edges) ------------------
    hipMemsetAsync(bcnt, 0, NBKT * sizeof(int), stream);
    k_bcount  <<<256,  256, 0, stream>>>(dst, E, bcnt);
    k_bscan   <<<1,    256, 0, stream>>>(bcnt, bbase, bcur);
    k_bscatter<<<768,  256, 0, stream>>>(src, dst, E, bcur, bpair);
    k_bcsc    <<<NBKT, 256, 0, stream>>>(bpair, bbase, rowptr, dinv, col, n);

    // ---- W prep -----------------------------------------------------------
    k_split_w2<<<128, 256, 0, stream>>>(W1, W2, wpk1, wpk2);

    // ---- layer 1 (f32 input fused into GEMM) ------------------------------
    k_gemm_mfma<1><<<nbGemm, 256, 0, stream>>>(x, wpk1, dinv, y, n, ntiles);
    k_agg3<0><<<nbAgg, 256, 0, stream>>>(y, rowptr, col, dinv, b1, h, n);

    // ---- layer 2 ----------------------------------------------------------
    k_gemm_mfma<0><<<nbGemm, 256, 0, stream>>>(h, wpk2, dinv, y, n, ntiles);
    k_agg3<1><<<nbAgg, 256, 0, stream>>>(y, rowptr, col, dinv, b2, out, n);
}